// Round 14
// baseline (2164.078 us; speedup 1.0000x reference)
//
#include <hip/hip_runtime.h>
#include <cstdint>
#include <cstddef>

#define B_ 64
#define S_ 512
#define IN_ 512
#define H_ 1024
#define NH_ 4
#define HD_ 256
#define A_ 18
#define HID_ 1024
#define TCH_ 128            // scan time-chunk
#define NCH_ (S_ / TCH_)    // 4 chunks

using short8 = __attribute__((ext_vector_type(8))) short;
using f32x4  = __attribute__((ext_vector_type(4))) float;

// ---------------- helpers ----------------
__device__ __forceinline__ unsigned short f2bf(float f) {
  union { float f; unsigned u; } c; c.f = f;
  unsigned r = c.u + 0x7FFFu + ((c.u >> 16) & 1u);  // RNE
  return (unsigned short)(r >> 16);
}
__device__ __forceinline__ float bf2f(unsigned short h) {
  union { unsigned u; float f; } c; c.u = ((unsigned)h) << 16;
  return c.f;
}
__device__ __forceinline__ unsigned pk2(float a, float b) {
  return (unsigned)f2bf(a) | ((unsigned)f2bf(b) << 16);
}
// packed-bf16 dual-MAC, h operand in SGPR (VOP3P allows one scalar source).
__device__ __forceinline__ float dot2s(unsigned r, unsigned h_sgpr, float c) {
  float d;
  asm("v_dot2_f32_bf16 %0, %1, %2, %3" : "=v"(d) : "v"(r), "s"(h_sgpr), "v"(c));
  return d;
}

// ---------------- R transcode: fp32 [nh][d][g][e] -> packed bf16 pairs ----------------
// Rbb[((nh*4+g)*256+e)*128 + dp] = pack(R[2dp], R[2dp+1])      (register part, dp<96)
// Rl flat uint: ((nh*1024+col)*8 + s)*4 + j  for dp = 96+4s+j  (LDS part, uint4-grouped)
__global__ __launch_bounds__(256) void rtrans_k(const float* __restrict__ R,
                                                unsigned* __restrict__ Rbb,
                                                unsigned* __restrict__ Rl) {
  const int i = blockIdx.x * 256 + threadIdx.x;   // [0, 524288)
  const int dp = i & 127;
  const int e = (i >> 7) & 255;
  const int g = (i >> 15) & 3;
  const int nh = i >> 17;
  const float* rp = R + (((size_t)nh * 256 + 2 * dp) * 4 + g) * 256 + e;  // d-stride 1024
  unsigned lo = f2bf(rp[0]), hi = f2bf(rp[1024]);
  unsigned v = lo | (hi << 16);
  Rbb[i] = v;
  if (dp >= 96) {
    int s = (dp - 96) >> 2, j = (dp - 96) & 3;
    int col = g * 256 + e;
    Rl[((size_t)(nh * 1024 + col) * 8 + s) * 4 + j] = v;
  }
}

// ---------------- w_gates transcode: fp32 [g][nh][d][e] -> bf16 [nh][g][e][d] ----------------
__global__ __launch_bounds__(256) void wgt_k(const float* __restrict__ wg,
                                             unsigned short* __restrict__ wgb) {
  const int i = blockIdx.x * 256 + threadIdx.x;   // [0, 1048576)
  const int k = i & 255;
  const int e = (i >> 8) & 255;
  const int g = (i >> 16) & 3;
  const int nh = i >> 18;
  wgb[i] = f2bf(wg[(((size_t)(g * 4 + nh) * 256 + k) * 256) + e]);
}

// ---------------- generic fp32 -> bf16 weight transcode (layout-preserving) ----------------
__global__ __launch_bounds__(256) void wbf_k(const float* __restrict__ src,
                                             unsigned short* __restrict__ dst, int n) {
  int i = blockIdx.x * 256 + threadIdx.x;
  if (i < n) dst[i] = f2bf(src[i]);
}

// ---------------- row stats for LN1 fusion (xproj is bf16) ----------------
__global__ __launch_bounds__(256) void rowstats_k(const unsigned short* __restrict__ x,
                                                  float* __restrict__ rs) {
  const int r = blockIdx.x, tid = threadIdx.x;
  const int lane = tid & 63, wave = tid >> 6;
  ushort4 u = *(const ushort4*)(x + (size_t)r * H_ + tid * 4);
  float v0 = bf2f(u.x), v1 = bf2f(u.y), v2 = bf2f(u.z), v3 = bf2f(u.w);
  float s1 = v0 + v1 + v2 + v3;
  float s2 = v0 * v0 + v1 * v1 + v2 * v2 + v3 * v3;
#pragma unroll
  for (int off = 32; off; off >>= 1) { s1 += __shfl_xor(s1, off); s2 += __shfl_xor(s2, off); }
  __shared__ float a1[4], a2[4];
  if (lane == 0) { a1[wave] = s1; a2[wave] = s2; }
  __syncthreads();
  if (tid == 0) {
    float S1 = a1[0] + a1[1] + a1[2] + a1[3];
    float S2 = a2[0] + a2[1] + a2[2] + a2[3];
    float mu = S1 * (1.f / H_);
    float var = S2 * (1.f / H_) - mu * mu;
    rs[r * 2] = mu;
    rs[r * 2 + 1] = rsqrtf(var + 1e-5f);
  }
}

// ---------------- MFMA bf16 GEMM, 128x128 tile, BK=32, 4 waves of 64x64 ----------------
// AMODE: 0 = A fp32 (cvt), 1 = A bf16 (ASYNC global_load_lds), 2 = A bf16 + fused LN
// BMODE: 0 = W fp32 (N,K), 1 = W bf16 gate-layout (ASYNC), 2 = W bf16 (N,K) (ASYNC)
template <int AMODE, int BMODE, bool RELU, int OUTMODE>
__global__ __launch_bounds__(256) void mgemm_k(
    const void* __restrict__ Av, const void* __restrict__ Wv,
    const float* __restrict__ bias, const float* __restrict__ rs,
    const float* __restrict__ lnw, unsigned short* __restrict__ Cb,
    int K, int lda, int chunk) {
  __shared__ uint4 As4[4][128];
  __shared__ uint4 Bs4[4][128];
  const int tid = threadIdx.x;
  const int lane = tid & 63, wave = tid >> 6;
  const int wr = wave >> 1, wc = wave & 1;
  const int col0 = blockIdx.y * 128;
  int nh = 0, g = 0, aoff = 0, bb = 0;
  size_t wbase = 0;
  if constexpr (OUTMODE == 1) {
    int z = blockIdx.z; nh = z >> 2; g = z & 3;
    aoff = nh * HD_;
    bb = blockIdx.x;
    wbase = (size_t)(nh * 4 + g) * 256 * 256;
  }
  auto arow = [&](int mm) -> int {
    if constexpr (OUTMODE == 1) return bb * 512 + chunk * TCH_ + mm;
    else return (int)blockIdx.x * 128 + mm;
  };
  f32x4 acc[4][4];
#pragma unroll
  for (int m = 0; m < 4; ++m)
#pragma unroll
    for (int n = 0; n < 4; ++n) acc[m][n] = 0.f;

  const int sm = tid >> 1;   // staging row (register paths)
  const int sh = tid & 1;    // k half (16 elems)

  for (int k0 = 0; k0 < K; k0 += 32) {
    // ---- stage A ----
    if constexpr (AMODE == 1) {
      // async: unit u = tid + h*256 -> As4[u>>7][u&127]; dest = wave-uniform base + lane*16
#pragma unroll
      for (int h2 = 0; h2 < 2; ++h2) {
        int u = tid + h2 * 256;
        int p = u >> 7, row = u & 127;
        const unsigned short* src = (const unsigned short*)Av + (size_t)arow(row) * lda + aoff + k0 + p * 8;
        __builtin_amdgcn_global_load_lds(
            (const __attribute__((address_space(1))) void*)src,
            (__attribute__((address_space(3))) void*)((uint4*)As4 + (tid >> 6) * 64 + h2 * 256),
            16, 0, 0);
      }
    } else {
      int rg = arow(sm);
      unsigned pk[8];
      if constexpr (AMODE == 0) {
        const float* ap = (const float*)Av + (size_t)rg * lda + k0 + sh * 16;
#pragma unroll
        for (int q = 0; q < 4; ++q) {
          float4 f = ((const float4*)ap)[q];
          pk[2 * q] = pk2(f.x, f.y); pk[2 * q + 1] = pk2(f.z, f.w);
        }
      } else {
        const uint4* ap = (const uint4*)((const unsigned short*)Av + (size_t)rg * lda + aoff + k0 + sh * 16);
        uint4 u0 = ap[0], u1 = ap[1];
        unsigned w8[8] = {u0.x, u0.y, u0.z, u0.w, u1.x, u1.y, u1.z, u1.w};
        float mu = rs[rg * 2], rstd = rs[rg * 2 + 1];
        const float* lw = lnw + aoff + k0 + sh * 16;
#pragma unroll
        for (int q = 0; q < 8; ++q) {
          float lo = (bf2f((unsigned short)w8[q]) - mu) * rstd * lw[2 * q];
          float hi = (bf2f((unsigned short)(w8[q] >> 16)) - mu) * rstd * lw[2 * q + 1];
          pk[q] = pk2(lo, hi);
        }
      }
      As4[2 * sh][sm]     = uint4{pk[0], pk[1], pk[2], pk[3]};
      As4[2 * sh + 1][sm] = uint4{pk[4], pk[5], pk[6], pk[7]};
    }
    // ---- stage B ----
    if constexpr (BMODE != 0) {
#pragma unroll
      for (int h2 = 0; h2 < 2; ++h2) {
        int u = tid + h2 * 256;
        int p = u >> 7, row = u & 127;
        const unsigned short* src;
        if constexpr (BMODE == 1)
          src = (const unsigned short*)Wv + wbase + (size_t)(col0 + row) * 256 + k0 + p * 8;
        else
          src = (const unsigned short*)Wv + (size_t)(col0 + row) * K + k0 + p * 8;
        __builtin_amdgcn_global_load_lds(
            (const __attribute__((address_space(1))) void*)src,
            (__attribute__((address_space(3))) void*)((uint4*)Bs4 + (tid >> 6) * 64 + h2 * 256),
            16, 0, 0);
      }
    } else {
      unsigned pk[8];
      const float* wp = (const float*)Wv + (size_t)(col0 + sm) * K + k0 + sh * 16;
#pragma unroll
      for (int q = 0; q < 4; ++q) {
        float4 f = ((const float4*)wp)[q];
        pk[2 * q] = pk2(f.x, f.y); pk[2 * q + 1] = pk2(f.z, f.w);
      }
      Bs4[2 * sh][sm]     = uint4{pk[0], pk[1], pk[2], pk[3]};
      Bs4[2 * sh + 1][sm] = uint4{pk[4], pk[5], pk[6], pk[7]};
    }
    __syncthreads();   // drains vmcnt (async LDS writes) + lgkm (ds writes)
    short8 af[4], bfv[4];
#pragma unroll
    for (int m = 0; m < 4; ++m)
      af[m] = *(const short8*)&As4[lane >> 4][wr * 64 + m * 16 + (lane & 15)];
#pragma unroll
    for (int n = 0; n < 4; ++n)
      bfv[n] = *(const short8*)&Bs4[lane >> 4][wc * 64 + n * 16 + (lane & 15)];
#pragma unroll
    for (int m = 0; m < 4; ++m)
#pragma unroll
      for (int n = 0; n < 4; ++n)
        acc[m][n] = __builtin_amdgcn_mfma_f32_16x16x32_bf16(af[m], bfv[n], acc[m][n], 0, 0, 0);
    __syncthreads();
  }
  if constexpr (OUTMODE == 0) {
#pragma unroll
    for (int n = 0; n < 4; ++n) {
      int c = col0 + wc * 64 + n * 16 + (lane & 15);
      float bc = bias ? bias[c] : 0.f;
#pragma unroll
      for (int m = 0; m < 4; ++m) {
        int r0 = arow(wr * 64 + m * 16 + ((lane >> 4) << 2));
#pragma unroll
        for (int i = 0; i < 4; ++i) {
          float v = acc[m][n][i] + bc;
          if constexpr (RELU) v = fmaxf(v, 0.f);
          Cb[(size_t)(r0 + i) * 1024 + c] = f2bf(v);
        }
      }
    }
  } else {
#pragma unroll
    for (int n = 0; n < 4; ++n) {
      int e = col0 + wc * 64 + n * 16 + (lane & 15);
#pragma unroll
      for (int m = 0; m < 4; ++m) {
        int sl0 = wr * 64 + m * 16 + ((lane >> 4) << 2);
#pragma unroll
        for (int i = 0; i < 4; ++i) {
          int sl = sl0 + i;
          size_t base = (size_t)(sl * 64 + bb) * 4096 + nh * 1024 + g * 256;
          Cb[base + e] = f2bf(acc[m][n][i]);
        }
      }
    }
  }
}

// ---------------- sLSTM scan: zero-exchange, 512 thr x 2 cols, register-broadcast h ----------
// Round-14: amdgpu_waves_per_eu(2,2) -> allocator may use 256 arch VGPRs so rc0+rc1
// (192 regs) stay un-parked (round 13's VGPR=128 forced ~64-96 regs into AGPRs, paying
// one v_accvgpr_read per dot2 -- the hidden ~2.5x VALU inflation).
__global__ __launch_bounds__(512)
__attribute__((amdgpu_waves_per_eu(2, 2)))
void scan_k(
    const unsigned short* __restrict__ gxc, const unsigned* __restrict__ Rbb,
    const unsigned* __restrict__ Rl, const float* __restrict__ bgates,
    float* __restrict__ state, unsigned short* __restrict__ y, int chunk) {
  const int tid = threadIdx.x;
  const int lane = tid & 63;
  const int bid = blockIdx.x;
  const int nh = bid >> 6, b = bid & 63;
  const int col0 = tid, col1 = tid + 512;
  const int g0 = col0 >> 8, g1 = col1 >> 8;        // wave-uniform
  __shared__ uint4 Rlds4[8][1024];                 // 128KB: R dp 96..127, [s][col]
  __shared__ float rawf[1024];                     // transformed raw[g*256+e]
  __shared__ alignas(16) unsigned short hsu[256];  // h packed bf16 (32 uint4 chunks)

  // fill Rlds4: 8192 uint4 by 512 threads = 16 iters (coalesced)
#pragma unroll
  for (int it = 0; it < 16; ++it) {
    int idx = it * 512 + tid;
    Rlds4[idx & 7][idx >> 3] = ((const uint4*)Rl)[(size_t)nh * 8192 + idx];
  }
  // register R for both columns: dp 0..95 each
  unsigned rc0[96], rc1[96];
  {
    const unsigned* rp0 = Rbb + ((size_t)nh * 1024 + col0) * 128;
    const unsigned* rp1 = Rbb + ((size_t)nh * 1024 + col1) * 128;
#pragma unroll
    for (int i = 0; i < 96; ++i) rc0[i] = rp0[i];
#pragma unroll
    for (int i = 0; i < 96; ++i) rc1[i] = rp1[i];
  }
  const float bg0 = bgates[g0 * H_ + nh * HD_ + (col0 & 255)];
  const float bg1 = bgates[g1 * H_ + nh * HD_ + (col1 & 255)];

  const size_t sbase = (size_t)b * H_ + nh * HD_ + tid;
  float c_ = 0.f, n_ = 0.f, m_ = 0.f, hlast = 0.f;
  if (tid < 256) {
    hlast = state[sbase];
    c_ = state[65536 + sbase];
    n_ = state[2 * 65536 + sbase];
    m_ = state[3 * 65536 + sbase];
    hsu[tid] = f2bf(hlast);
  }
  __syncthreads();

  const unsigned short* gp0 = gxc + ((size_t)b * 4 + nh) * 1024 + col0;
  const unsigned short* gp1 = gp0 + 512;
  unsigned short* yp = y + ((size_t)(chunk * TCH_) * 64 + b) * H_ + nh * HD_;

  unsigned short gc0 = gp0[0], gc1 = gp1[0];

  for (int t = 0; t < TCH_; ++t) {
    float a0a = bf2f(gc0) + bg0, a0b = 0.f;        // 4 independent dot2 chains
    float a1a = bf2f(gc1) + bg1, a1b = 0.f;
    if (t < TCH_ - 1) {  // prefetch under matvec
      gc0 = gp0[(size_t)(t + 1) * 262144];
      gc1 = gp1[(size_t)(t + 1) * 262144];
    }
    // ONE LDS read of this lane's h chunk; chunk pairs broadcast across half-waves
    uint4 hc = ((const uint4*)hsu)[lane & 31];
    // register part: chunks q=0..23 (dp = 4q+j), h via readlane -> SGPR
#pragma unroll
    for (int q = 0; q < 24; ++q) {
      unsigned h0 = __builtin_amdgcn_readlane(hc.x, q);
      unsigned h1 = __builtin_amdgcn_readlane(hc.y, q);
      unsigned h2 = __builtin_amdgcn_readlane(hc.z, q);
      unsigned h3 = __builtin_amdgcn_readlane(hc.w, q);
      a0a = dot2s(rc0[4 * q + 0], h0, a0a);
      a1a = dot2s(rc1[4 * q + 0], h0, a1a);
      a0a = dot2s(rc0[4 * q + 1], h1, a0a);
      a1a = dot2s(rc1[4 * q + 1], h1, a1a);
      a0b = dot2s(rc0[4 * q + 2], h2, a0b);
      a1b = dot2s(rc1[4 * q + 2], h2, a1b);
      a0b = dot2s(rc0[4 * q + 3], h3, a0b);
      a1b = dot2s(rc1[4 * q + 3], h3, a1b);
    }
    // LDS part: chunks q=24..31 (dp = 96+4s+j), R from Rlds4 (b128)
#pragma unroll
    for (int s = 0; s < 8; ++s) {
      int q = 24 + s;
      unsigned h0 = __builtin_amdgcn_readlane(hc.x, q);
      unsigned h1 = __builtin_amdgcn_readlane(hc.y, q);
      unsigned h2 = __builtin_amdgcn_readlane(hc.z, q);
      unsigned h3 = __builtin_amdgcn_readlane(hc.w, q);
      uint4 ra = Rlds4[s][col0];
      uint4 rb = Rlds4[s][col1];
      a0a = dot2s(ra.x, h0, a0a);
      a1a = dot2s(rb.x, h0, a1a);
      a0a = dot2s(ra.y, h1, a0a);
      a1a = dot2s(rb.y, h1, a1a);
      a0b = dot2s(ra.z, h2, a0b);
      a1b = dot2s(rb.z, h2, a1b);
      a0b = dot2s(ra.w, h3, a0b);
      a1b = dot2s(rb.w, h3, a1b);
    }
    float acc0 = a0a + a0b;
    float acc1 = a1a + a1b;
    // gate-local transforms (wave-uniform branches)
    float val0, val1;
    if (g0 == 0) {
      val0 = acc0;                                  // iraw
    } else {
      float ls = -log1pf(expf(-fabsf(acc0)));       // log_sigmoid(fraw)
      if (acc0 < 0.f) ls += acc0;
      val0 = ls;
    }
    if (g1 == 2) {
      val1 = tanhf(acc1);                           // tanh(zraw)
    } else {
      val1 = 1.f / (1.f + expf(-acc1));             // sigmoid(oraw)
    }
    rawf[col0] = val0;
    rawf[col1] = val1;
    __syncthreads();
    if (tid < 256) {   // owner: 2 exp + mul/div
      float iraw = rawf[tid];
      float ls   = rawf[256 + tid];
      float tz   = rawf[512 + tid];
      float sg   = rawf[768 + tid];
      float lfm = m_ + ls;
      float mnew = fmaxf(iraw, lfm);
      float iv = expf(iraw - mnew);
      float fv = expf(lfm - mnew);
      c_ = fv * c_ + iv * tz;
      n_ = fv * n_ + iv;
      m_ = mnew;
      hlast = sg * c_ / n_;
      unsigned short hb = f2bf(hlast);
      hsu[tid] = hb;
      yp[(size_t)t * 65536 + tid] = hb;            // y[s][b][h] bf16
    }
    __syncthreads();
  }
  if (tid < 256) {
    state[sbase] = hlast;
    state[65536 + sbase] = c_;
    state[2 * 65536 + sbase] = n_;
    state[3 * 65536 + sbase] = m_;
  }
}

// ---------------- groupnorm + residual + post LN (bf16 in/out) ----------------
__global__ __launch_bounds__(256) void post_k(
    const unsigned short* __restrict__ y, const unsigned short* __restrict__ xp,
    const float* __restrict__ gnw, const float* __restrict__ lpw,
    unsigned short* __restrict__ outb) {
  const int r = blockIdx.x;            // r = b*512 + s
  const int b = r >> 9, s = r & 511;
  const int tid = threadIdx.x;
  const int lane = tid & 63, wave = tid >> 6;
  ushort4 yu = *(const ushort4*)(y + (size_t)(s * 64 + b) * H_ + tid * 4);
  float v[4] = {bf2f(yu.x), bf2f(yu.y), bf2f(yu.z), bf2f(yu.w)};
  float s1 = v[0] + v[1] + v[2] + v[3];
  float s2 = v[0] * v[0] + v[1] * v[1] + v[2] * v[2] + v[3] * v[3];
#pragma unroll
  for (int off = 32; off; off >>= 1) { s1 += __shfl_xor(s1, off); s2 += __shfl_xor(s2, off); }
  float mu = s1 * (1.f / HD_);
  float rstd = rsqrtf(s2 * (1.f / HD_) - mu * mu + 1e-5f);
  float4 g4 = *(const float4*)(gnw + tid * 4);
  ushort4 xu = *(const ushort4*)(xp + (size_t)r * H_ + tid * 4);
  float o[4];
  o[0] = fmaf((v[0] - mu) * rstd, g4.x, bf2f(xu.x));
  o[1] = fmaf((v[1] - mu) * rstd, g4.y, bf2f(xu.y));
  o[2] = fmaf((v[2] - mu) * rstd, g4.z, bf2f(xu.z));
  o[3] = fmaf((v[3] - mu) * rstd, g4.w, bf2f(xu.w));
  float t1 = o[0] + o[1] + o[2] + o[3];
  float t2 = o[0] * o[0] + o[1] * o[1] + o[2] * o[2] + o[3] * o[3];
#pragma unroll
  for (int off = 32; off; off >>= 1) { t1 += __shfl_xor(t1, off); t2 += __shfl_xor(t2, off); }
  __shared__ float a1[4], a2[4];
  if (lane == 0) { a1[wave] = t1; a2[wave] = t2; }
  __syncthreads();
  float T1 = a1[0] + a1[1] + a1[2] + a1[3];
  float T2 = a2[0] + a2[1] + a2[2] + a2[3];
  float MU = T1 * (1.f / H_);
  float RS = rsqrtf(T2 * (1.f / H_) - MU * MU + 1e-5f);
  float4 w4 = *(const float4*)(lpw + tid * 4);
  ushort4 res = {f2bf((o[0] - MU) * RS * w4.x), f2bf((o[1] - MU) * RS * w4.y),
                 f2bf((o[2] - MU) * RS * w4.z), f2bf((o[3] - MU) * RS * w4.w)};
  *(ushort4*)(outb + (size_t)r * H_ + tid * 4) = res;
}

// ---------------- logits + value heads (bf16 in, fp32 out) ----------------
__global__ __launch_bounds__(256) void heads_k(
    const unsigned short* __restrict__ hp, const unsigned short* __restrict__ hv,
    const float* __restrict__ Wact, const float* __restrict__ bact,
    const float* __restrict__ Wv, const float* __restrict__ bv,
    float* __restrict__ dout) {
  const int lane = threadIdx.x & 63, wave = threadIdx.x >> 6;
  const int r = blockIdx.x * 4 + wave;
  const unsigned short* hpr = hp + (size_t)r * HID_;
  const unsigned short* hvr = hv + (size_t)r * HID_;
  float acc[A_];
#pragma unroll
  for (int j = 0; j < A_; ++j) acc[j] = 0.f;
  float accv = 0.f;
  for (int i = 0; i < 16; ++i) {
    int k = i * 64 + lane;
    float hpv = bf2f(hpr[k]);
    float hvv = bf2f(hvr[k]);
#pragma unroll
    for (int j = 0; j < A_; ++j) acc[j] = fmaf(hpv, Wact[j * HID_ + k], acc[j]);
    accv = fmaf(hvv, Wv[k], accv);
  }
#pragma unroll
  for (int j = 0; j < A_; ++j)
#pragma unroll
    for (int off = 32; off; off >>= 1) acc[j] += __shfl_xor(acc[j], off);
#pragma unroll
  for (int off = 32; off; off >>= 1) accv += __shfl_xor(accv, off);
  if (lane == 0) {
#pragma unroll
    for (int j = 0; j < A_; ++j) dout[(size_t)r * A_ + j] = acc[j] + bact[j];
    dout[589824 + r] = accv + bv[0];
  }
}

// ---------------- launch ----------------
extern "C" void kernel_launch(void* const* d_in, const int* in_sizes, int n_in,
                              void* d_out, int out_size, void* d_ws, size_t ws_size,
                              hipStream_t stream) {
  const float* obs   = (const float*)d_in[0];
  const float* st    = (const float*)d_in[1];
  const float* W_in  = (const float*)d_in[2];
  const float* b_in  = (const float*)d_in[3];
  const float* ln1w  = (const float*)d_in[4];
  const float* wg    = (const float*)d_in[5];
  const float* R     = (const float*)d_in[6];
  const float* bgat  = (const float*)d_in[7];
  const float* gnw   = (const float*)d_in[8];
  const float* lpw   = (const float*)d_in[9];
  const float* W_hid = (const float*)d_in[10];
  const float* b_hid = (const float*)d_in[11];
  const float* W_pol = (const float*)d_in[12];
  const float* b_pol = (const float*)d_in[13];
  const float* W_val = (const float*)d_in[14];
  const float* b_val = (const float*)d_in[15];
  const float* W_act = (const float*)d_in[16];
  const float* b_act = (const float*)d_in[17];
  const float* W_v   = (const float*)d_in[18];
  const float* b_v   = (const float*)d_in[19];

  // Workspace layout (identical offsets to round 13):
  //  A [0,        67108864): xproj bf16  -> hh bf16
  //  B [67108864, 134217728): gx chunk bf16 (T=128) -> outb bf16 -> hv bf16
  //  C [134217728,201326592): y bf16 -> hp bf16
  //  ST[201326592,202375168): scan state fp32 (h,c,n,m) 4x64x1024
  //  RS[202375168,202899456): LN1 row stats
  //  RB[202899456,204996608): R packed bf16 pairs (register part source)
  //  WG[204996608,207093760): w_gates bf16 [nh][g][e][k]
  //  RL[207093760,207618048): R LDS-part (uint4-grouped)
  //  WI[207618048,208666624): W_in  bf16
  //  WH[208666624,210763776): W_hid bf16
  //  WP[210763776,212860928): W_pol bf16
  //  WV[212860928,214958080): W_val bf16
  const size_t NEEDED = 214958080;
  if (ws_size < NEEDED) return;
  char* ws = (char*)d_ws;
  unsigned short* xproj = (unsigned short*)(ws + 0);
  unsigned short* gxc   = (unsigned short*)(ws + 67108864);
  unsigned short* ybuf  = (unsigned short*)(ws + 134217728);
  float* statebuf       = (float*)(ws + 201326592);
  float* rstat          = (float*)(ws + 202375168);
  unsigned* Rbb         = (unsigned*)(ws + 202899456);
  unsigned short* wgb   = (unsigned short*)(ws + 204996608);
  unsigned* Rl          = (unsigned*)(ws + 207093760);
  unsigned short* wib   = (unsigned short*)(ws + 207618048);
  unsigned short* whb   = (unsigned short*)(ws + 208666624);
  unsigned short* wpb   = (unsigned short*)(ws + 210763776);
  unsigned short* wvb   = (unsigned short*)(ws + 212860928);
  unsigned short* outb  = gxc;
  unsigned short* hh    = xproj;
  unsigned short* hp    = ybuf;
  unsigned short* hv    = gxc;
  float* dout = (float*)d_out;

  hipMemcpyAsync(statebuf, st, 4 * 65536 * sizeof(float), hipMemcpyDeviceToDevice, stream);
  rtrans_k<<<2048, 256, 0, stream>>>(R, Rbb, Rl);
  wgt_k<<<4096, 256, 0, stream>>>(wg, wgb);
  wbf_k<<<2048, 256, 0, stream>>>(W_in, wib, 524288);
  wbf_k<<<4096, 256, 0, stream>>>(W_hid, whb, 1048576);
  wbf_k<<<4096, 256, 0, stream>>>(W_pol, wpb, 1048576);
  wbf_k<<<4096, 256, 0, stream>>>(W_val, wvb, 1048576);
  mgemm_k<0, 2, false, 0><<<dim3(256, 8), 256, 0, stream>>>(
      obs, wib, b_in, nullptr, nullptr, xproj, 512, 512, 0);
  rowstats_k<<<32768, 256, 0, stream>>>(xproj, rstat);
  for (int c = 0; c < NCH_; ++c) {
    mgemm_k<2, 1, false, 1><<<dim3(64, 2, 16), 256, 0, stream>>>(
        xproj, wgb, nullptr, rstat, ln1w, gxc, 256, 1024, c);
    scan_k<<<256, 512, 0, stream>>>(gxc, Rbb, Rl, bgat, statebuf, ybuf, c);
  }
  post_k<<<32768, 256, 0, stream>>>(ybuf, xproj, gnw, lpw, outb);
  mgemm_k<1, 2, true, 0><<<dim3(256, 8), 256, 0, stream>>>(
      outb, whb, b_hid, nullptr, nullptr, hh, 1024, 1024, 0);
  mgemm_k<1, 2, true, 0><<<dim3(256, 8), 256, 0, stream>>>(
      hh, wpb, b_pol, nullptr, nullptr, hp, 1024, 1024, 0);
  mgemm_k<1, 2, true, 0><<<dim3(256, 8), 256, 0, stream>>>(
      hh, wvb, b_val, nullptr, nullptr, hv, 1024, 1024, 0);
  heads_k<<<8192, 256, 0, stream>>>(hp, hv, W_act, b_act, W_v, b_v, dout);
}

// Round 15
// 1903.940 us; speedup vs baseline: 1.1366x; 1.1366x over previous
//
#include <hip/hip_runtime.h>
#include <cstdint>
#include <cstddef>

#define B_ 64
#define S_ 512
#define IN_ 512
#define H_ 1024
#define NH_ 4
#define HD_ 256
#define A_ 18
#define HID_ 1024
#define TCH_ 128            // scan time-chunk
#define NCH_ (S_ / TCH_)    // 4 chunks

using short8 = __attribute__((ext_vector_type(8))) short;
using f32x4  = __attribute__((ext_vector_type(4))) float;

// ---------------- helpers ----------------
__device__ __forceinline__ unsigned short f2bf(float f) {
  union { float f; unsigned u; } c; c.f = f;
  unsigned r = c.u + 0x7FFFu + ((c.u >> 16) & 1u);  // RNE
  return (unsigned short)(r >> 16);
}
__device__ __forceinline__ float bf2f(unsigned short h) {
  union { unsigned u; float f; } c; c.u = ((unsigned)h) << 16;
  return c.f;
}
__device__ __forceinline__ unsigned pk2(float a, float b) {
  return (unsigned)f2bf(a) | ((unsigned)f2bf(b) << 16);
}
// packed-bf16 dual-MAC, h operand in SGPR (VOP3P allows one scalar source).
__device__ __forceinline__ float dot2s(unsigned r, unsigned h_sgpr, float c) {
  float d;
  asm("v_dot2_f32_bf16 %0, %1, %2, %3" : "=v"(d) : "v"(r), "s"(h_sgpr), "v"(c));
  return d;
}

// ---------------- R transcode: fp32 [nh][d][g][e] -> packed bf16 pairs ----------------
// Rbb[((nh*4+g)*256+e)*128 + dp] = pack(R[2dp], R[2dp+1])      (register part, dp<96)
// Rl flat uint: ((nh*1024+col)*8 + s)*4 + j  for dp = 96+4s+j  (LDS part, uint4-grouped)
__global__ __launch_bounds__(256) void rtrans_k(const float* __restrict__ R,
                                                unsigned* __restrict__ Rbb,
                                                unsigned* __restrict__ Rl) {
  const int i = blockIdx.x * 256 + threadIdx.x;   // [0, 524288)
  const int dp = i & 127;
  const int e = (i >> 7) & 255;
  const int g = (i >> 15) & 3;
  const int nh = i >> 17;
  const float* rp = R + (((size_t)nh * 256 + 2 * dp) * 4 + g) * 256 + e;  // d-stride 1024
  unsigned lo = f2bf(rp[0]), hi = f2bf(rp[1024]);
  unsigned v = lo | (hi << 16);
  Rbb[i] = v;
  if (dp >= 96) {
    int s = (dp - 96) >> 2, j = (dp - 96) & 3;
    int col = g * 256 + e;
    Rl[((size_t)(nh * 1024 + col) * 8 + s) * 4 + j] = v;
  }
}

// ---------------- w_gates transcode: fp32 [g][nh][d][e] -> bf16 [nh][g][e][d] ----------------
__global__ __launch_bounds__(256) void wgt_k(const float* __restrict__ wg,
                                             unsigned short* __restrict__ wgb) {
  const int i = blockIdx.x * 256 + threadIdx.x;   // [0, 1048576)
  const int k = i & 255;
  const int e = (i >> 8) & 255;
  const int g = (i >> 16) & 3;
  const int nh = i >> 18;
  wgb[i] = f2bf(wg[(((size_t)(g * 4 + nh) * 256 + k) * 256) + e]);
}

// ---------------- generic fp32 -> bf16 weight transcode (layout-preserving) ----------------
__global__ __launch_bounds__(256) void wbf_k(const float* __restrict__ src,
                                             unsigned short* __restrict__ dst, int n) {
  int i = blockIdx.x * 256 + threadIdx.x;
  if (i < n) dst[i] = f2bf(src[i]);
}

// ---------------- row stats for LN1 fusion (xproj is bf16) ----------------
__global__ __launch_bounds__(256) void rowstats_k(const unsigned short* __restrict__ x,
                                                  float* __restrict__ rs) {
  const int r = blockIdx.x, tid = threadIdx.x;
  const int lane = tid & 63, wave = tid >> 6;
  ushort4 u = *(const ushort4*)(x + (size_t)r * H_ + tid * 4);
  float v0 = bf2f(u.x), v1 = bf2f(u.y), v2 = bf2f(u.z), v3 = bf2f(u.w);
  float s1 = v0 + v1 + v2 + v3;
  float s2 = v0 * v0 + v1 * v1 + v2 * v2 + v3 * v3;
#pragma unroll
  for (int off = 32; off; off >>= 1) { s1 += __shfl_xor(s1, off); s2 += __shfl_xor(s2, off); }
  __shared__ float a1[4], a2[4];
  if (lane == 0) { a1[wave] = s1; a2[wave] = s2; }
  __syncthreads();
  if (tid == 0) {
    float S1 = a1[0] + a1[1] + a1[2] + a1[3];
    float S2 = a2[0] + a2[1] + a2[2] + a2[3];
    float mu = S1 * (1.f / H_);
    float var = S2 * (1.f / H_) - mu * mu;
    rs[r * 2] = mu;
    rs[r * 2 + 1] = rsqrtf(var + 1e-5f);
  }
}

// ---------------- MFMA bf16 GEMM, 128x128 tile, BK=32, 4 waves of 64x64 ----------------
// (round-13 register-staged version: the round-14 global_load_lds variant regressed
//  ~150us -- 16B/lane row-strided sources scatter into 64 transactions per instr)
// AMODE: 0 = A fp32 (cvt), 1 = A bf16, 2 = A bf16 + fused LN
// BMODE: 0 = W fp32 (N,K), 1 = W bf16 gate-layout [col][256], 2 = W bf16 (N,K) stride K
template <int AMODE, int BMODE, bool RELU, int OUTMODE>
__global__ __launch_bounds__(256) void mgemm_k(
    const void* __restrict__ Av, const void* __restrict__ Wv,
    const float* __restrict__ bias, const float* __restrict__ rs,
    const float* __restrict__ lnw, unsigned short* __restrict__ Cb,
    int K, int lda, int chunk) {
  __shared__ uint4 As4[4][128];
  __shared__ uint4 Bs4[4][128];
  const int tid = threadIdx.x;
  const int lane = tid & 63, wave = tid >> 6;
  const int wr = wave >> 1, wc = wave & 1;
  const int col0 = blockIdx.y * 128;
  int nh = 0, g = 0, aoff = 0, bb = 0;
  size_t wbase = 0;
  if constexpr (OUTMODE == 1) {
    int z = blockIdx.z; nh = z >> 2; g = z & 3;
    aoff = nh * HD_;
    bb = blockIdx.x;
    wbase = (size_t)(nh * 4 + g) * 256 * 256;
  }
  auto arow = [&](int mm) -> int {
    if constexpr (OUTMODE == 1) return bb * 512 + chunk * TCH_ + mm;
    else return (int)blockIdx.x * 128 + mm;
  };
  f32x4 acc[4][4];
#pragma unroll
  for (int m = 0; m < 4; ++m)
#pragma unroll
    for (int n = 0; n < 4; ++n) acc[m][n] = 0.f;

  const int sm = tid >> 1;   // staging row
  const int sh = tid & 1;    // k half (16 elems)

  for (int k0 = 0; k0 < K; k0 += 32) {
    {
      int rg = arow(sm);
      unsigned pk[8];
      if constexpr (AMODE == 0) {
        const float* ap = (const float*)Av + (size_t)rg * lda + k0 + sh * 16;
#pragma unroll
        for (int q = 0; q < 4; ++q) {
          float4 f = ((const float4*)ap)[q];
          pk[2 * q] = pk2(f.x, f.y); pk[2 * q + 1] = pk2(f.z, f.w);
        }
      } else if constexpr (AMODE == 1) {
        const uint4* ap = (const uint4*)((const unsigned short*)Av + (size_t)rg * lda + aoff + k0 + sh * 16);
        uint4 u0 = ap[0], u1 = ap[1];
        pk[0] = u0.x; pk[1] = u0.y; pk[2] = u0.z; pk[3] = u0.w;
        pk[4] = u1.x; pk[5] = u1.y; pk[6] = u1.z; pk[7] = u1.w;
      } else {
        const uint4* ap = (const uint4*)((const unsigned short*)Av + (size_t)rg * lda + aoff + k0 + sh * 16);
        uint4 u0 = ap[0], u1 = ap[1];
        unsigned w8[8] = {u0.x, u0.y, u0.z, u0.w, u1.x, u1.y, u1.z, u1.w};
        float mu = rs[rg * 2], rstd = rs[rg * 2 + 1];
        const float* lw = lnw + aoff + k0 + sh * 16;
#pragma unroll
        for (int q = 0; q < 8; ++q) {
          float lo = (bf2f((unsigned short)w8[q]) - mu) * rstd * lw[2 * q];
          float hi = (bf2f((unsigned short)(w8[q] >> 16)) - mu) * rstd * lw[2 * q + 1];
          pk[q] = pk2(lo, hi);
        }
      }
      As4[2 * sh][sm]     = uint4{pk[0], pk[1], pk[2], pk[3]};
      As4[2 * sh + 1][sm] = uint4{pk[4], pk[5], pk[6], pk[7]};
    }
    {
      unsigned pk[8];
      if constexpr (BMODE == 0) {
        const float* wp = (const float*)Wv + (size_t)(col0 + sm) * K + k0 + sh * 16;
#pragma unroll
        for (int q = 0; q < 4; ++q) {
          float4 f = ((const float4*)wp)[q];
          pk[2 * q] = pk2(f.x, f.y); pk[2 * q + 1] = pk2(f.z, f.w);
        }
      } else if constexpr (BMODE == 1) {
        const uint4* wp = (const uint4*)((const unsigned short*)Wv + wbase + (size_t)(col0 + sm) * 256 + k0 + sh * 16);
        uint4 u0 = wp[0], u1 = wp[1];
        pk[0] = u0.x; pk[1] = u0.y; pk[2] = u0.z; pk[3] = u0.w;
        pk[4] = u1.x; pk[5] = u1.y; pk[6] = u1.z; pk[7] = u1.w;
      } else {
        const uint4* wp = (const uint4*)((const unsigned short*)Wv + (size_t)(col0 + sm) * K + k0 + sh * 16);
        uint4 u0 = wp[0], u1 = wp[1];
        pk[0] = u0.x; pk[1] = u0.y; pk[2] = u0.z; pk[3] = u0.w;
        pk[4] = u1.x; pk[5] = u1.y; pk[6] = u1.z; pk[7] = u1.w;
      }
      Bs4[2 * sh][sm]     = uint4{pk[0], pk[1], pk[2], pk[3]};
      Bs4[2 * sh + 1][sm] = uint4{pk[4], pk[5], pk[6], pk[7]};
    }
    __syncthreads();
    short8 af[4], bfv[4];
#pragma unroll
    for (int m = 0; m < 4; ++m)
      af[m] = *(const short8*)&As4[lane >> 4][wr * 64 + m * 16 + (lane & 15)];
#pragma unroll
    for (int n = 0; n < 4; ++n)
      bfv[n] = *(const short8*)&Bs4[lane >> 4][wc * 64 + n * 16 + (lane & 15)];
#pragma unroll
    for (int m = 0; m < 4; ++m)
#pragma unroll
      for (int n = 0; n < 4; ++n)
        acc[m][n] = __builtin_amdgcn_mfma_f32_16x16x32_bf16(af[m], bfv[n], acc[m][n], 0, 0, 0);
    __syncthreads();
  }
  if constexpr (OUTMODE == 0) {
#pragma unroll
    for (int n = 0; n < 4; ++n) {
      int c = col0 + wc * 64 + n * 16 + (lane & 15);
      float bc = bias ? bias[c] : 0.f;
#pragma unroll
      for (int m = 0; m < 4; ++m) {
        int r0 = arow(wr * 64 + m * 16 + ((lane >> 4) << 2));
#pragma unroll
        for (int i = 0; i < 4; ++i) {
          float v = acc[m][n][i] + bc;
          if constexpr (RELU) v = fmaxf(v, 0.f);
          Cb[(size_t)(r0 + i) * 1024 + c] = f2bf(v);
        }
      }
    }
  } else {
#pragma unroll
    for (int n = 0; n < 4; ++n) {
      int e = col0 + wc * 64 + n * 16 + (lane & 15);
#pragma unroll
      for (int m = 0; m < 4; ++m) {
        int sl0 = wr * 64 + m * 16 + ((lane >> 4) << 2);
#pragma unroll
        for (int i = 0; i < 4; ++i) {
          int sl = sl0 + i;
          size_t base = (size_t)(sl * 64 + bb) * 4096 + nh * 1024 + g * 256;
          Cb[base + e] = f2bf(acc[m][n][i]);
        }
      }
    }
  }
}

// ---------------- sLSTM scan: zero-exchange, 512 thr x 2 cols, register-broadcast h ----------
// Round-15: gate-transform branches scalarized via readfirstlane (previously the
// compiler exec-masked BOTH sides -- every wave paid log_sigmoid + tanh + sigmoid);
// cheap exp-based tanh / log1p replacements.
__global__ __launch_bounds__(512, 2) void scan_k(
    const unsigned short* __restrict__ gxc, const unsigned* __restrict__ Rbb,
    const unsigned* __restrict__ Rl, const float* __restrict__ bgates,
    float* __restrict__ state, unsigned short* __restrict__ y, int chunk) {
  const int tid = threadIdx.x;
  const int lane = tid & 63;
  const int bid = blockIdx.x;
  const int nh = bid >> 6, b = bid & 63;
  const int col0 = tid, col1 = tid + 512;
  // wave-uniform gate selectors, made provably scalar for the compiler
  const int gsel0 = __builtin_amdgcn_readfirstlane(col0 >> 8);
  const int gsel1 = __builtin_amdgcn_readfirstlane(col1 >> 8);
  __shared__ uint4 Rlds4[8][1024];                 // 128KB: R dp 96..127, [s][col]
  __shared__ float rawf[1024];                     // transformed raw[g*256+e]
  __shared__ alignas(16) unsigned short hsu[256];  // h packed bf16 (32 uint4 chunks)

  // fill Rlds4: 8192 uint4 by 512 threads = 16 iters (coalesced)
#pragma unroll
  for (int it = 0; it < 16; ++it) {
    int idx = it * 512 + tid;
    Rlds4[idx & 7][idx >> 3] = ((const uint4*)Rl)[(size_t)nh * 8192 + idx];
  }
  // register R for both columns: dp 0..95 each
  unsigned rc0[96], rc1[96];
  {
    const unsigned* rp0 = Rbb + ((size_t)nh * 1024 + col0) * 128;
    const unsigned* rp1 = Rbb + ((size_t)nh * 1024 + col1) * 128;
#pragma unroll
    for (int i = 0; i < 96; ++i) rc0[i] = rp0[i];
#pragma unroll
    for (int i = 0; i < 96; ++i) rc1[i] = rp1[i];
  }
  const float bg0 = bgates[gsel0 * H_ + nh * HD_ + (col0 & 255)];
  const float bg1 = bgates[gsel1 * H_ + nh * HD_ + (col1 & 255)];

  const size_t sbase = (size_t)b * H_ + nh * HD_ + tid;
  float c_ = 0.f, n_ = 0.f, m_ = 0.f, hlast = 0.f;
  if (tid < 256) {
    hlast = state[sbase];
    c_ = state[65536 + sbase];
    n_ = state[2 * 65536 + sbase];
    m_ = state[3 * 65536 + sbase];
    hsu[tid] = f2bf(hlast);
  }
  __syncthreads();

  const unsigned short* gp0 = gxc + ((size_t)b * 4 + nh) * 1024 + col0;
  const unsigned short* gp1 = gp0 + 512;
  unsigned short* yp = y + ((size_t)(chunk * TCH_) * 64 + b) * H_ + nh * HD_;

  unsigned short gc0 = gp0[0], gc1 = gp1[0];

  for (int t = 0; t < TCH_; ++t) {
    float a0a = bf2f(gc0) + bg0, a0b = 0.f;        // 4 independent dot2 chains
    float a1a = bf2f(gc1) + bg1, a1b = 0.f;
    if (t < TCH_ - 1) {  // prefetch under matvec
      gc0 = gp0[(size_t)(t + 1) * 262144];
      gc1 = gp1[(size_t)(t + 1) * 262144];
    }
    // ONE LDS read of this lane's h chunk; chunk pairs broadcast across half-waves
    uint4 hc = ((const uint4*)hsu)[lane & 31];
    // register part: chunks q=0..23 (dp = 4q+j), h via readlane -> SGPR
#pragma unroll
    for (int q = 0; q < 24; ++q) {
      unsigned h0 = __builtin_amdgcn_readlane(hc.x, q);
      unsigned h1 = __builtin_amdgcn_readlane(hc.y, q);
      unsigned h2 = __builtin_amdgcn_readlane(hc.z, q);
      unsigned h3 = __builtin_amdgcn_readlane(hc.w, q);
      a0a = dot2s(rc0[4 * q + 0], h0, a0a);
      a1a = dot2s(rc1[4 * q + 0], h0, a1a);
      a0a = dot2s(rc0[4 * q + 1], h1, a0a);
      a1a = dot2s(rc1[4 * q + 1], h1, a1a);
      a0b = dot2s(rc0[4 * q + 2], h2, a0b);
      a1b = dot2s(rc1[4 * q + 2], h2, a1b);
      a0b = dot2s(rc0[4 * q + 3], h3, a0b);
      a1b = dot2s(rc1[4 * q + 3], h3, a1b);
    }
    // LDS part: chunks q=24..31 (dp = 96+4s+j), R from Rlds4 (b128)
#pragma unroll
    for (int s = 0; s < 8; ++s) {
      int q = 24 + s;
      unsigned h0 = __builtin_amdgcn_readlane(hc.x, q);
      unsigned h1 = __builtin_amdgcn_readlane(hc.y, q);
      unsigned h2 = __builtin_amdgcn_readlane(hc.z, q);
      unsigned h3 = __builtin_amdgcn_readlane(hc.w, q);
      uint4 ra = Rlds4[s][col0];
      uint4 rb = Rlds4[s][col1];
      a0a = dot2s(ra.x, h0, a0a);
      a1a = dot2s(rb.x, h0, a1a);
      a0a = dot2s(ra.y, h1, a0a);
      a1a = dot2s(rb.y, h1, a1a);
      a0b = dot2s(ra.z, h2, a0b);
      a1b = dot2s(rb.z, h2, a1b);
      a0b = dot2s(ra.w, h3, a0b);
      a1b = dot2s(rb.w, h3, a1b);
    }
    float acc0 = a0a + a0b;
    float acc1 = a1a + a1b;
    // gate-local transforms (scalar branches via gsel)
    float val0, val1;
    if (gsel0 == 0) {
      val0 = acc0;                                  // iraw
    } else {
      float e = expf(-fabsf(acc0));                 // log_sigmoid(fraw)
      val0 = fminf(acc0, 0.f) - logf(1.f + e);
    }
    if (gsel1 == 2) {
      float t2z = expf(2.f * acc1);                 // tanh(zraw) = (t-1)/(t+1)
      val1 = 1.f - 2.f / (t2z + 1.f);
    } else {
      val1 = 1.f / (1.f + expf(-acc1));             // sigmoid(oraw)
    }
    rawf[col0] = val0;
    rawf[col1] = val1;
    __syncthreads();
    if (tid < 256) {   // owner: 2 exp + mul/div
      float iraw = rawf[tid];
      float ls   = rawf[256 + tid];
      float tz   = rawf[512 + tid];
      float sg   = rawf[768 + tid];
      float lfm = m_ + ls;
      float mnew = fmaxf(iraw, lfm);
      float iv = expf(iraw - mnew);
      float fv = expf(lfm - mnew);
      c_ = fv * c_ + iv * tz;
      n_ = fv * n_ + iv;
      m_ = mnew;
      hlast = sg * c_ / n_;
      unsigned short hb = f2bf(hlast);
      hsu[tid] = hb;
      yp[(size_t)t * 65536 + tid] = hb;            // y[s][b][h] bf16
    }
    __syncthreads();
  }
  if (tid < 256) {
    state[sbase] = hlast;
    state[65536 + sbase] = c_;
    state[2 * 65536 + sbase] = n_;
    state[3 * 65536 + sbase] = m_;
  }
}

// ---------------- groupnorm + residual + post LN (bf16 in/out) ----------------
__global__ __launch_bounds__(256) void post_k(
    const unsigned short* __restrict__ y, const unsigned short* __restrict__ xp,
    const float* __restrict__ gnw, const float* __restrict__ lpw,
    unsigned short* __restrict__ outb) {
  const int r = blockIdx.x;            // r = b*512 + s
  const int b = r >> 9, s = r & 511;
  const int tid = threadIdx.x;
  const int lane = tid & 63, wave = tid >> 6;
  ushort4 yu = *(const ushort4*)(y + (size_t)(s * 64 + b) * H_ + tid * 4);
  float v[4] = {bf2f(yu.x), bf2f(yu.y), bf2f(yu.z), bf2f(yu.w)};
  float s1 = v[0] + v[1] + v[2] + v[3];
  float s2 = v[0] * v[0] + v[1] * v[1] + v[2] * v[2] + v[3] * v[3];
#pragma unroll
  for (int off = 32; off; off >>= 1) { s1 += __shfl_xor(s1, off); s2 += __shfl_xor(s2, off); }
  float mu = s1 * (1.f / HD_);
  float rstd = rsqrtf(s2 * (1.f / HD_) - mu * mu + 1e-5f);
  float4 g4 = *(const float4*)(gnw + tid * 4);
  ushort4 xu = *(const ushort4*)(xp + (size_t)r * H_ + tid * 4);
  float o[4];
  o[0] = fmaf((v[0] - mu) * rstd, g4.x, bf2f(xu.x));
  o[1] = fmaf((v[1] - mu) * rstd, g4.y, bf2f(xu.y));
  o[2] = fmaf((v[2] - mu) * rstd, g4.z, bf2f(xu.z));
  o[3] = fmaf((v[3] - mu) * rstd, g4.w, bf2f(xu.w));
  float t1 = o[0] + o[1] + o[2] + o[3];
  float t2 = o[0] * o[0] + o[1] * o[1] + o[2] * o[2] + o[3] * o[3];
#pragma unroll
  for (int off = 32; off; off >>= 1) { t1 += __shfl_xor(t1, off); t2 += __shfl_xor(t2, off); }
  __shared__ float a1[4], a2[4];
  if (lane == 0) { a1[wave] = t1; a2[wave] = t2; }
  __syncthreads();
  float T1 = a1[0] + a1[1] + a1[2] + a1[3];
  float T2 = a2[0] + a2[1] + a2[2] + a2[3];
  float MU = T1 * (1.f / H_);
  float RS = rsqrtf(T2 * (1.f / H_) - MU * MU + 1e-5f);
  float4 w4 = *(const float4*)(lpw + tid * 4);
  ushort4 res = {f2bf((o[0] - MU) * RS * w4.x), f2bf((o[1] - MU) * RS * w4.y),
                 f2bf((o[2] - MU) * RS * w4.z), f2bf((o[3] - MU) * RS * w4.w)};
  *(ushort4*)(outb + (size_t)r * H_ + tid * 4) = res;
}

// ---------------- logits + value heads (bf16 in, fp32 out) ----------------
__global__ __launch_bounds__(256) void heads_k(
    const unsigned short* __restrict__ hp, const unsigned short* __restrict__ hv,
    const float* __restrict__ Wact, const float* __restrict__ bact,
    const float* __restrict__ Wv, const float* __restrict__ bv,
    float* __restrict__ dout) {
  const int lane = threadIdx.x & 63, wave = threadIdx.x >> 6;
  const int r = blockIdx.x * 4 + wave;
  const unsigned short* hpr = hp + (size_t)r * HID_;
  const unsigned short* hvr = hv + (size_t)r * HID_;
  float acc[A_];
#pragma unroll
  for (int j = 0; j < A_; ++j) acc[j] = 0.f;
  float accv = 0.f;
  for (int i = 0; i < 16; ++i) {
    int k = i * 64 + lane;
    float hpv = bf2f(hpr[k]);
    float hvv = bf2f(hvr[k]);
#pragma unroll
    for (int j = 0; j < A_; ++j) acc[j] = fmaf(hpv, Wact[j * HID_ + k], acc[j]);
    accv = fmaf(hvv, Wv[k], accv);
  }
#pragma unroll
  for (int j = 0; j < A_; ++j)
#pragma unroll
    for (int off = 32; off; off >>= 1) acc[j] += __shfl_xor(acc[j], off);
#pragma unroll
  for (int off = 32; off; off >>= 1) accv += __shfl_xor(accv, off);
  if (lane == 0) {
#pragma unroll
    for (int j = 0; j < A_; ++j) dout[(size_t)r * A_ + j] = acc[j] + bact[j];
    dout[589824 + r] = accv + bv[0];
  }
}

// ---------------- launch ----------------
extern "C" void kernel_launch(void* const* d_in, const int* in_sizes, int n_in,
                              void* d_out, int out_size, void* d_ws, size_t ws_size,
                              hipStream_t stream) {
  const float* obs   = (const float*)d_in[0];
  const float* st    = (const float*)d_in[1];
  const float* W_in  = (const float*)d_in[2];
  const float* b_in  = (const float*)d_in[3];
  const float* ln1w  = (const float*)d_in[4];
  const float* wg    = (const float*)d_in[5];
  const float* R     = (const float*)d_in[6];
  const float* bgat  = (const float*)d_in[7];
  const float* gnw   = (const float*)d_in[8];
  const float* lpw   = (const float*)d_in[9];
  const float* W_hid = (const float*)d_in[10];
  const float* b_hid = (const float*)d_in[11];
  const float* W_pol = (const float*)d_in[12];
  const float* b_pol = (const float*)d_in[13];
  const float* W_val = (const float*)d_in[14];
  const float* b_val = (const float*)d_in[15];
  const float* W_act = (const float*)d_in[16];
  const float* b_act = (const float*)d_in[17];
  const float* W_v   = (const float*)d_in[18];
  const float* b_v   = (const float*)d_in[19];

  // Workspace layout (identical offsets to round 13):
  //  A [0,        67108864): xproj bf16  -> hh bf16
  //  B [67108864, 134217728): gx chunk bf16 (T=128) -> outb bf16 -> hv bf16
  //  C [134217728,201326592): y bf16 -> hp bf16
  //  ST[201326592,202375168): scan state fp32 (h,c,n,m) 4x64x1024
  //  RS[202375168,202899456): LN1 row stats
  //  RB[202899456,204996608): R packed bf16 pairs (register part source)
  //  WG[204996608,207093760): w_gates bf16 [nh][g][e][k]
  //  RL[207093760,207618048): R LDS-part (uint4-grouped)
  //  WI[207618048,208666624): W_in  bf16
  //  WH[208666624,210763776): W_hid bf16
  //  WP[210763776,212860928): W_pol bf16
  //  WV[212860928,214958080): W_val bf16
  const size_t NEEDED = 214958080;
  if (ws_size < NEEDED) return;
  char* ws = (char*)d_ws;
  unsigned short* xproj = (unsigned short*)(ws + 0);
  unsigned short* gxc   = (unsigned short*)(ws + 67108864);
  unsigned short* ybuf  = (unsigned short*)(ws + 134217728);
  float* statebuf       = (float*)(ws + 201326592);
  float* rstat          = (float*)(ws + 202375168);
  unsigned* Rbb         = (unsigned*)(ws + 202899456);
  unsigned short* wgb   = (unsigned short*)(ws + 204996608);
  unsigned* Rl          = (unsigned*)(ws + 207093760);
  unsigned short* wib   = (unsigned short*)(ws + 207618048);
  unsigned short* whb   = (unsigned short*)(ws + 208666624);
  unsigned short* wpb   = (unsigned short*)(ws + 210763776);
  unsigned short* wvb   = (unsigned short*)(ws + 212860928);
  unsigned short* outb  = gxc;
  unsigned short* hh    = xproj;
  unsigned short* hp    = ybuf;
  unsigned short* hv    = gxc;
  float* dout = (float*)d_out;

  hipMemcpyAsync(statebuf, st, 4 * 65536 * sizeof(float), hipMemcpyDeviceToDevice, stream);
  rtrans_k<<<2048, 256, 0, stream>>>(R, Rbb, Rl);
  wgt_k<<<4096, 256, 0, stream>>>(wg, wgb);
  wbf_k<<<2048, 256, 0, stream>>>(W_in, wib, 524288);
  wbf_k<<<4096, 256, 0, stream>>>(W_hid, whb, 1048576);
  wbf_k<<<4096, 256, 0, stream>>>(W_pol, wpb, 1048576);
  wbf_k<<<4096, 256, 0, stream>>>(W_val, wvb, 1048576);
  mgemm_k<0, 2, false, 0><<<dim3(256, 8), 256, 0, stream>>>(
      obs, wib, b_in, nullptr, nullptr, xproj, 512, 512, 0);
  rowstats_k<<<32768, 256, 0, stream>>>(xproj, rstat);
  for (int c = 0; c < NCH_; ++c) {
    mgemm_k<2, 1, false, 1><<<dim3(64, 2, 16), 256, 0, stream>>>(
        xproj, wgb, nullptr, rstat, ln1w, gxc, 256, 1024, c);
    scan_k<<<256, 512, 0, stream>>>(gxc, Rbb, Rl, bgat, statebuf, ybuf, c);
  }
  post_k<<<32768, 256, 0, stream>>>(ybuf, xproj, gnw, lpw, outb);
  mgemm_k<1, 2, true, 0><<<dim3(256, 8), 256, 0, stream>>>(
      outb, whb, b_hid, nullptr, nullptr, hh, 1024, 1024, 0);
  mgemm_k<1, 2, true, 0><<<dim3(256, 8), 256, 0, stream>>>(
      hh, wpb, b_pol, nullptr, nullptr, hp, 1024, 1024, 0);
  mgemm_k<1, 2, true, 0><<<dim3(256, 8), 256, 0, stream>>>(
      hh, wvb, b_val, nullptr, nullptr, hv, 1024, 1024, 0);
  heads_k<<<8192, 256, 0, stream>>>(hp, hv, W_act, b_act, W_v, b_v, dout);
}